// Round 1
// baseline (604.249 us; speedup 1.0000x reference)
//
#include <hip/hip_runtime.h>
#include <cstdint>
#include <cstddef>

#define NN 207      // nodes
#define NE 1722     // edges
#define NT 24       // time buckets (288/12)
#define LL 2048     // L
#define LC 64       // L-chunk per block
#define EPMAX 2560  // padded edge capacity per direction (E + 3N = 2343 <= 2560)

// ---------------- ws layout (bytes) ----------------
// rp_f    @ 0        : int[256]   (N+1 used) from-sorted row ptrs (padded to x4)
// rp_t    @ 1024     : int[256]
// perm_f  @ 2048     : int[EPMAX] edge id per padded slot, -1 = pad
// nbr_f   @ 12288    : int[EPMAX] neighbor (to[e]) pre-scaled by LC
// perm_t  @ 22528    : int[EPMAX]
// nbr_t   @ 32768    : int[EPMAX] neighbor (from[e]) pre-scaled by LC
// ef      @ 43008    : float4[NT*EPMAX] {nbr_as_int_bits, wr, wra, 0} from-sorted
// et      @ 1026048  : float4[NT*EPMAX] {nbr_as_int_bits, wd, wda, 0} to-sorted
// ct4     @ 2009088  : float4[NT*NN]   {c_r, c_ra, c_d, c_da}
// bb4     @ 2088576  : float4[NT*NN]   {b_r, b_ra, b_d, b_da}
// total 2168064 bytes (~2.07 MB)

__device__ __forceinline__ float tanh_fast(float x) {
    float e = __expf(2.0f * x);                 // inf for large x -> 1; 0 for very neg -> -1
    return 1.0f - __fdividef(2.0f, e + 1.0f);
}

// K1: padded CSR in both directions. Single block of 256 threads.
__global__ void k_build_csr(const int* __restrict__ efrom, const int* __restrict__ eto,
                            int* __restrict__ rp_f, int* __restrict__ rp_t,
                            int* __restrict__ perm_f, int* __restrict__ nbr_f,
                            int* __restrict__ perm_t, int* __restrict__ nbr_t) {
    __shared__ int cf[NN], ctn[NN], curf[NN], curt[NN];
    const int tid = threadIdx.x;
    for (int w = tid; w < NN; w += 256) { cf[w] = 0; ctn[w] = 0; }
    __syncthreads();
    for (int e = tid; e < NE; e += 256) {
        atomicAdd(&cf[efrom[e]], 1);
        atomicAdd(&ctn[eto[e]], 1);
    }
    __syncthreads();
    if (tid == 0) {      // exclusive scan with per-row pad to multiple of 4
        int p = 0;
        for (int w = 0; w < NN; w++) { rp_f[w] = p; curf[w] = p; p += (cf[w] + 3) & ~3; }
        rp_f[NN] = p;
    }
    if (tid == 64) {
        int p = 0;
        for (int w = 0; w < NN; w++) { rp_t[w] = p; curt[w] = p; p += (ctn[w] + 3) & ~3; }
        rp_t[NN] = p;
    }
    __syncthreads();
    for (int j = tid; j < EPMAX; j += 256) { perm_f[j] = -1; perm_t[j] = -1; }
    __syncthreads();
    for (int e = tid; e < NE; e += 256) {
        int w  = efrom[e];
        int p  = atomicAdd(&curf[w], 1);
        perm_f[p] = e; nbr_f[p] = eto[e] * LC;
        int w2 = eto[e];
        int p2 = atomicAdd(&curt[w2], 1);
        perm_t[p2] = e; nbr_t[p2] = efrom[e] * LC;
    }
}

// K2: per-t packed edge records (from-sorted: reaction pair; to-sorted: diffusion pair)
__global__ void k_build_records(const int* __restrict__ rp_f, const int* __restrict__ rp_t,
                                const int* __restrict__ perm_f, const int* __restrict__ nbr_f,
                                const int* __restrict__ perm_t, const int* __restrict__ nbr_t,
                                const float* __restrict__ wr, const float* __restrict__ wra,
                                const float* __restrict__ wd, const float* __restrict__ wda,
                                float4* __restrict__ ef, float4* __restrict__ et) {
    int gid = blockIdx.x * 256 + threadIdx.x;     // NT*EPMAX threads exactly
    int t = gid / EPMAX;
    int j = gid - t * EPMAX;
    if (t >= NT) return;
    int plf = rp_f[NN], plt = rp_t[NN];
    if (j < plf) {
        int eid = perm_f[j];
        float4 r;
        if (eid >= 0) { r.x = __int_as_float(nbr_f[j]); r.y = wr[t * NE + eid]; r.z = wra[t * NE + eid]; }
        else          { r.x = __int_as_float(0);        r.y = 0.0f;             r.z = 0.0f; }
        r.w = 0.0f;
        ef[(size_t)t * EPMAX + j] = r;
    }
    if (j < plt) {
        int eid = perm_t[j];
        float4 r;
        if (eid >= 0) { r.x = __int_as_float(nbr_t[j]); r.y = wd[t * NE + eid]; r.z = wda[t * NE + eid]; }
        else          { r.x = __int_as_float(0);        r.y = 0.0f;             r.z = 0.0f; }
        r.w = 0.0f;
        et[(size_t)t * EPMAX + j] = r;
    }
}

// K3: per-(t,w) diag coefficients (colsums) + packed biases
__global__ void k_build_tables(const int* __restrict__ rp_f, const int* __restrict__ rp_t,
                               const int* __restrict__ perm_f, const int* __restrict__ perm_t,
                               const float* __restrict__ wr, const float* __restrict__ wra,
                               const float* __restrict__ wd, const float* __restrict__ wda,
                               const float* __restrict__ br, const float* __restrict__ bd,
                               const float* __restrict__ bra, const float* __restrict__ bda,
                               float4* __restrict__ ct4, float4* __restrict__ bb4) {
    int gid = blockIdx.x * 256 + threadIdx.x;     // gid = t*NN + w
    if (gid >= NT * NN) return;
    int t = gid / NN;
    int w = gid - t * NN;
    float cr = 0.0f, cra = 0.0f, cd = 0.0f, cda = 0.0f;
    for (int j = rp_t[w]; j < rp_t[w + 1]; j++) {   // edges with to==w
        int eid = perm_t[j];
        if (eid >= 0) { cr += wr[t * NE + eid]; cra += wra[t * NE + eid]; }
    }
    for (int j = rp_f[w]; j < rp_f[w + 1]; j++) {   // edges with from==w
        int eid = perm_f[j];
        if (eid >= 0) { cd += wd[t * NE + eid]; cda += wda[t * NE + eid]; }
    }
    ct4[gid] = make_float4(cr, cra, cd, cda);
    bb4[gid] = make_float4(br[gid], bra[gid], bd[gid], bda[gid]);
}

// Main kernel: block = (batch b, L-chunk). 256 threads = 4 waves; one w per wave,
// lane = l within the 64-wide chunk. x tile staged in LDS (207*64*4 = 53 KB -> 3 blocks/CU).
__global__ __launch_bounds__(256, 3) void k_main(
    const float* __restrict__ inputs, const int* __restrict__ ind,
    const int* __restrict__ rp_f, const int* __restrict__ rp_t,
    const float4* __restrict__ ef, const float4* __restrict__ et,
    const float4* __restrict__ ct4, const float4* __restrict__ bb4,
    float* __restrict__ out) {
    __shared__ float xs[NN * LC];
    const int b     = blockIdx.y;
    const int chunk = blockIdx.x;
    const int tid   = threadIdx.x;
    const int t     = ind[b] / 12;       // uniform (blockIdx-derived) -> SGPR

    // stage x[b, 0, :, chunk*64 .. +64) into LDS, float4-vectorized
    const float* xbase = inputs + ((size_t)b * 2 * NN) * LL + (size_t)chunk * LC;
    for (int i = tid; i < NN * (LC / 4); i += 256) {
        int row = i >> 4;
        int c4  = (i & 15) << 2;
        float4 v = *(const float4*)(xbase + (size_t)row * LL + c4);
        *(float4*)(&xs[row * LC + c4]) = v;
    }
    __syncthreads();

    const int l  = tid & 63;
    const int w0 = __builtin_amdgcn_readfirstlane(tid >> 6);  // force wave-uniform w -> scalar loads
    const float4* eft = ef + (size_t)t * EPMAX;
    const float4* ett = et + (size_t)t * EPMAX;
    const int tN = t * NN;
    float* outb = out + ((size_t)b * NN) * LL + (size_t)chunk * LC + l;

    for (int w = w0; w < NN; w += 4) {
        float4 cc = ct4[tN + w];
        float4 bb = bb4[tN + w];
        float cra = (b == 0) ? 0.0f : cc.y;   // batch-0 special case: colsum(RW[0]) == 0
        float xw = xs[w * LC + l];
        float r  = fmaf(cc.x, xw, bb.x);
        float ra = fmaf(cra,  xw, bb.y);
        float d  = fmaf(cc.z, xw, bb.z);
        float da = fmaf(cc.w, xw, bb.w);

        int j0 = rp_f[w], j1 = rp_f[w + 1];   // padded to x4; pads have zero weights
        for (int j = j0; j < j1; j += 4) {
            float4 e0 = eft[j], e1 = eft[j + 1], e2 = eft[j + 2], e3 = eft[j + 3];
            float x0 = xs[__float_as_int(e0.x) + l];
            float x1 = xs[__float_as_int(e1.x) + l];
            float x2 = xs[__float_as_int(e2.x) + l];
            float x3 = xs[__float_as_int(e3.x) + l];
            r = fmaf(-e0.y, x0, r); ra = fmaf(e0.z, x0, ra);
            r = fmaf(-e1.y, x1, r); ra = fmaf(e1.z, x1, ra);
            r = fmaf(-e2.y, x2, r); ra = fmaf(e2.z, x2, ra);
            r = fmaf(-e3.y, x3, r); ra = fmaf(e3.z, x3, ra);
        }
        j0 = rp_t[w]; j1 = rp_t[w + 1];
        for (int j = j0; j < j1; j += 4) {
            float4 e0 = ett[j], e1 = ett[j + 1], e2 = ett[j + 2], e3 = ett[j + 3];
            float x0 = xs[__float_as_int(e0.x) + l];
            float x1 = xs[__float_as_int(e1.x) + l];
            float x2 = xs[__float_as_int(e2.x) + l];
            float x3 = xs[__float_as_int(e3.x) + l];
            d = fmaf(-e0.y, x0, d); da = fmaf(e0.z, x0, da);
            d = fmaf(-e1.y, x1, d); da = fmaf(e1.z, x1, da);
            d = fmaf(-e2.y, x2, d); da = fmaf(e2.z, x2, da);
            d = fmaf(-e3.y, x3, d); da = fmaf(e3.z, x3, da);
        }
        float o = tanh_fast(r) + tanh_fast(ra) + d + da + xw;
        outb[(size_t)w * LL] = o;
    }
}

extern "C" void kernel_launch(void* const* d_in, const int* in_sizes, int n_in,
                              void* d_out, int out_size, void* d_ws, size_t ws_size,
                              hipStream_t stream) {
    const float* inputs = (const float*)d_in[0];
    const int*   ind    = (const int*)d_in[1];
    const int*   efrom  = (const int*)d_in[2];
    const int*   eto    = (const int*)d_in[3];
    const float* wr     = (const float*)d_in[4];   // weight_react
    const float* wd     = (const float*)d_in[5];   // weight_diff
    const float* wra    = (const float*)d_in[6];   // weight_react_a
    const float* wda    = (const float*)d_in[7];   // weight_diff_a
    const float* br     = (const float*)d_in[8];   // bias_reaction
    const float* bd     = (const float*)d_in[9];   // bias_diffusion
    const float* bra    = (const float*)d_in[10];  // bias_reaction_a
    const float* bda    = (const float*)d_in[11];  // bias_diffusion_a
    float* out = (float*)d_out;

    char* ws = (char*)d_ws;
    int*    rp_f   = (int*)(ws + 0);
    int*    rp_t   = (int*)(ws + 1024);
    int*    perm_f = (int*)(ws + 2048);
    int*    nbr_f  = (int*)(ws + 12288);
    int*    perm_t = (int*)(ws + 22528);
    int*    nbr_t  = (int*)(ws + 32768);
    float4* ef     = (float4*)(ws + 43008);
    float4* et     = (float4*)(ws + 1026048);
    float4* ct4    = (float4*)(ws + 2009088);
    float4* bb4    = (float4*)(ws + 2088576);

    const int B = in_sizes[1];   // 64

    k_build_csr<<<dim3(1), dim3(256), 0, stream>>>(efrom, eto, rp_f, rp_t,
                                                   perm_f, nbr_f, perm_t, nbr_t);
    k_build_records<<<dim3(NT * EPMAX / 256), dim3(256), 0, stream>>>(
        rp_f, rp_t, perm_f, nbr_f, perm_t, nbr_t, wr, wra, wd, wda, ef, et);
    k_build_tables<<<dim3((NT * NN + 255) / 256), dim3(256), 0, stream>>>(
        rp_f, rp_t, perm_f, perm_t, wr, wra, wd, wda, br, bd, bra, bda, ct4, bb4);
    k_main<<<dim3(LL / LC, B), dim3(256), 0, stream>>>(
        inputs, ind, rp_f, rp_t, ef, et, ct4, bb4, out);
}

// Round 3
// 548.752 us; speedup vs baseline: 1.1011x; 1.1011x over previous
//
#include <hip/hip_runtime.h>
#include <cstdint>
#include <cstddef>

#define NN 207      // nodes
#define NE 1722     // edges
#define NT 24       // time buckets (288/12)
#define LL 2048     // L
#define LC 64       // dwords per LDS row (= 128 bf16 columns per block)
#define LCC 128     // columns per block
#define EPMAX 2560  // padded edge capacity per direction (E + 3N = 2343 <= 2560)

// ---------------- ws layout (bytes) ----------------
// rp_f    @ 0        : int[256]   (N+1 used) from-sorted row ptrs (padded to x4)
// rp_t    @ 1024     : int[256]
// perm_f  @ 2048     : int[EPMAX] edge id per padded slot, -1 = pad
// nbr_f   @ 12288    : int[EPMAX] neighbor (to[e]) pre-scaled by LC (dwords/row)
// perm_t  @ 22528    : int[EPMAX]
// nbr_t   @ 32768    : int[EPMAX] neighbor (from[e]) pre-scaled by LC
// ef      @ 43008    : float4[NT*EPMAX] {nbr_as_int_bits, wr, wra, 0} from-sorted
// et      @ 1026048  : float4[NT*EPMAX] {nbr_as_int_bits, wd, wda, 0} to-sorted
// ct4     @ 2009088  : float4[NT*NN]   {c_r, c_ra, c_d, c_da}
// bb4     @ 2088576  : float4[NT*NN]   {b_r, b_ra, b_d, b_da}
// total 2168064 bytes (~2.07 MB)

typedef float f2 __attribute__((ext_vector_type(2)));

__device__ __forceinline__ f2 tanh2(f2 x) {
    f2 o;
    float ex = __expf(2.0f * x.x), ey = __expf(2.0f * x.y);
    o.x = 1.0f - __fdividef(2.0f, ex + 1.0f);
    o.y = 1.0f - __fdividef(2.0f, ey + 1.0f);
    return o;
}

__device__ __forceinline__ f2 up2(unsigned int u) {   // dword of 2 bf16 -> f2
    f2 v;
    v.x = __uint_as_float(u << 16);
    v.y = __uint_as_float(u & 0xffff0000u);
    return v;
}

__device__ __forceinline__ unsigned short bf16_rne(float f) {  // manual RNE f32->bf16
    unsigned int u = __float_as_uint(f);
    u += 0x7FFFu + ((u >> 16) & 1u);
    return (unsigned short)(u >> 16);
}

__device__ __forceinline__ f2 fma2(float s, f2 x, f2 a) {
    f2 sv = s;                    // splat
    return __builtin_elementwise_fma(sv, x, a);
}

// K1: padded CSR in both directions. Single block of 256 threads.
__global__ void k_build_csr(const int* __restrict__ efrom, const int* __restrict__ eto,
                            int* __restrict__ rp_f, int* __restrict__ rp_t,
                            int* __restrict__ perm_f, int* __restrict__ nbr_f,
                            int* __restrict__ perm_t, int* __restrict__ nbr_t) {
    __shared__ int cf[NN], ctn[NN], curf[NN], curt[NN];
    const int tid = threadIdx.x;
    for (int w = tid; w < NN; w += 256) { cf[w] = 0; ctn[w] = 0; }
    __syncthreads();
    for (int e = tid; e < NE; e += 256) {
        atomicAdd(&cf[efrom[e]], 1);
        atomicAdd(&ctn[eto[e]], 1);
    }
    __syncthreads();
    if (tid == 0) {      // exclusive scan with per-row pad to multiple of 4
        int p = 0;
        for (int w = 0; w < NN; w++) { rp_f[w] = p; curf[w] = p; p += (cf[w] + 3) & ~3; }
        rp_f[NN] = p;
    }
    if (tid == 64) {
        int p = 0;
        for (int w = 0; w < NN; w++) { rp_t[w] = p; curt[w] = p; p += (ctn[w] + 3) & ~3; }
        rp_t[NN] = p;
    }
    __syncthreads();
    for (int j = tid; j < EPMAX; j += 256) { perm_f[j] = -1; perm_t[j] = -1; }
    __syncthreads();
    for (int e = tid; e < NE; e += 256) {
        int w  = efrom[e];
        int p  = atomicAdd(&curf[w], 1);
        perm_f[p] = e; nbr_f[p] = eto[e] * LC;
        int w2 = eto[e];
        int p2 = atomicAdd(&curt[w2], 1);
        perm_t[p2] = e; nbr_t[p2] = efrom[e] * LC;
    }
}

// K2: per-t packed edge records
__global__ void k_build_records(const int* __restrict__ rp_f, const int* __restrict__ rp_t,
                                const int* __restrict__ perm_f, const int* __restrict__ nbr_f,
                                const int* __restrict__ perm_t, const int* __restrict__ nbr_t,
                                const float* __restrict__ wr, const float* __restrict__ wra,
                                const float* __restrict__ wd, const float* __restrict__ wda,
                                float4* __restrict__ ef, float4* __restrict__ et) {
    int gid = blockIdx.x * 256 + threadIdx.x;     // NT*EPMAX threads exactly
    int t = gid / EPMAX;
    int j = gid - t * EPMAX;
    if (t >= NT) return;
    int plf = rp_f[NN], plt = rp_t[NN];
    if (j < plf) {
        int eid = perm_f[j];
        float4 r;
        if (eid >= 0) { r.x = __int_as_float(nbr_f[j]); r.y = wr[t * NE + eid]; r.z = wra[t * NE + eid]; }
        else          { r.x = __int_as_float(0);        r.y = 0.0f;             r.z = 0.0f; }
        r.w = 0.0f;
        ef[(size_t)t * EPMAX + j] = r;
    }
    if (j < plt) {
        int eid = perm_t[j];
        float4 r;
        if (eid >= 0) { r.x = __int_as_float(nbr_t[j]); r.y = wd[t * NE + eid]; r.z = wda[t * NE + eid]; }
        else          { r.x = __int_as_float(0);        r.y = 0.0f;             r.z = 0.0f; }
        r.w = 0.0f;
        et[(size_t)t * EPMAX + j] = r;
    }
}

// K3: per-(t,w) diag coefficients (colsums) + packed biases
__global__ void k_build_tables(const int* __restrict__ rp_f, const int* __restrict__ rp_t,
                               const int* __restrict__ perm_f, const int* __restrict__ perm_t,
                               const float* __restrict__ wr, const float* __restrict__ wra,
                               const float* __restrict__ wd, const float* __restrict__ wda,
                               const float* __restrict__ br, const float* __restrict__ bd,
                               const float* __restrict__ bra, const float* __restrict__ bda,
                               float4* __restrict__ ct4, float4* __restrict__ bb4) {
    int gid = blockIdx.x * 256 + threadIdx.x;     // gid = t*NN + w
    if (gid >= NT * NN) return;
    int t = gid / NN;
    int w = gid - t * NN;
    float cr = 0.0f, cra = 0.0f, cd = 0.0f, cda = 0.0f;
    for (int j = rp_t[w]; j < rp_t[w + 1]; j++) {   // edges with to==w
        int eid = perm_t[j];
        if (eid >= 0) { cr += wr[t * NE + eid]; cra += wra[t * NE + eid]; }
    }
    for (int j = rp_f[w]; j < rp_f[w + 1]; j++) {   // edges with from==w
        int eid = perm_f[j];
        if (eid >= 0) { cd += wd[t * NE + eid]; cda += wda[t * NE + eid]; }
    }
    ct4[gid] = make_float4(cr, cra, cd, cda);
    bb4[gid] = make_float4(br[gid], bra[gid], bd[gid], bda[gid]);
}

// Main kernel: block = (128-col chunk, batch b). 256 threads = 4 waves.
// Lane l owns columns (2l, 2l+1) of the chunk; wave g handles rows w ≡ g (mod 4),
// two rows in flight per iteration (w, w+104) for MLP.
// NOTE: w is derived from threadIdx (divergent to the compiler) ON PURPOSE —
// round 1's readfirstlane forced s_loads whose serialized misses cost 274K cyc/block.
__global__ __launch_bounds__(256, 3) void k_main(
    const float* __restrict__ inputs, const int* __restrict__ ind,
    const int* __restrict__ rp_f, const int* __restrict__ rp_t,
    const float4* __restrict__ ef, const float4* __restrict__ et,
    const float4* __restrict__ ct4, const float4* __restrict__ bb4,
    float* __restrict__ out) {
    __shared__ unsigned short xsu[NN * LCC];      // bf16 x-tile, 52992 B -> 3 blocks/CU
    const int b     = blockIdx.y;
    const int chunk = blockIdx.x;
    const int tid   = threadIdx.x;
    const int t     = ind[b] / 12;

    // stage x[b,0,:,chunk*128 .. +128) into LDS as bf16
    const float* xbase = inputs + ((size_t)b * 2 * NN) * LL + (size_t)chunk * LCC;
    for (int i = tid; i < NN * 32; i += 256) {    // 207 rows x 32 float4
        int row = i >> 5;
        int c4  = (i & 31) << 2;
        float4 v = *(const float4*)(xbase + (size_t)row * LL + c4);
        ushort4 h;
        h.x = bf16_rne(v.x);
        h.y = bf16_rne(v.y);
        h.z = bf16_rne(v.z);
        h.w = bf16_rne(v.w);
        *(ushort4*)&xsu[row * LCC + c4] = h;
    }
    __syncthreads();

    const unsigned int* xsw = (const unsigned int*)xsu;
    const int l  = tid & 63;
    const int w0 = tid >> 6;                      // NOT readfirstlane: keep loads vector
    const float4* eft  = ef  + (size_t)t * EPMAX;
    const float4* ett  = et  + (size_t)t * EPMAX;
    const float4* ct4p = ct4 + (size_t)t * NN;
    const float4* bb4p = bb4 + (size_t)t * NN;
    float* outb = out + ((size_t)b * NN) * LL + (size_t)chunk * LCC + 2 * l;

    for (int k = 0; k < 26; k++) {
        const int wa = w0 + 4 * k;        // 0..103, always valid
        const int wb = wa + 104;          // 104..207, guard last
        const bool hb = (wb < NN);

        // issue both rows' header loads up front (independent chains)
        int af0 = rp_f[wa], af1 = rp_f[wa + 1], at0 = rp_t[wa], at1 = rp_t[wa + 1];
        float4 cca = ct4p[wa], bba = bb4p[wa];
        int bf0 = 0, bf1 = 0, bt0 = 0, bt1 = 0;
        float4 ccb = make_float4(0, 0, 0, 0), bbb = make_float4(0, 0, 0, 0);
        if (hb) {
            bf0 = rp_f[wb]; bf1 = rp_f[wb + 1]; bt0 = rp_t[wb]; bt1 = rp_t[wb + 1];
            ccb = ct4p[wb]; bbb = bb4p[wb];
        }

        // ---- row a ----
        {
            f2 xw = up2(xsw[wa * LC + l]);
            float cra = (b == 0) ? 0.0f : cca.y;   // colsum(RW[0]) == 0 analytically
            f2 r  = fma2(cca.x, xw, (f2)bba.x);
            f2 ra = fma2(cra,   xw, (f2)bba.y);
            f2 d  = fma2(cca.z, xw, (f2)bba.z);
            f2 da = fma2(cca.w, xw, (f2)bba.w);
            for (int j = af0; j < af1; j += 4) {
                float4 e0 = eft[j], e1 = eft[j + 1], e2 = eft[j + 2], e3 = eft[j + 3];
                f2 x0 = up2(xsw[__float_as_int(e0.x) + l]);
                f2 x1 = up2(xsw[__float_as_int(e1.x) + l]);
                f2 x2 = up2(xsw[__float_as_int(e2.x) + l]);
                f2 x3 = up2(xsw[__float_as_int(e3.x) + l]);
                r = fma2(-e0.y, x0, r); ra = fma2(e0.z, x0, ra);
                r = fma2(-e1.y, x1, r); ra = fma2(e1.z, x1, ra);
                r = fma2(-e2.y, x2, r); ra = fma2(e2.z, x2, ra);
                r = fma2(-e3.y, x3, r); ra = fma2(e3.z, x3, ra);
            }
            for (int j = at0; j < at1; j += 4) {
                float4 e0 = ett[j], e1 = ett[j + 1], e2 = ett[j + 2], e3 = ett[j + 3];
                f2 x0 = up2(xsw[__float_as_int(e0.x) + l]);
                f2 x1 = up2(xsw[__float_as_int(e1.x) + l]);
                f2 x2 = up2(xsw[__float_as_int(e2.x) + l]);
                f2 x3 = up2(xsw[__float_as_int(e3.x) + l]);
                d = fma2(-e0.y, x0, d); da = fma2(e0.z, x0, da);
                d = fma2(-e1.y, x1, d); da = fma2(e1.z, x1, da);
                d = fma2(-e2.y, x2, d); da = fma2(e2.z, x2, da);
                d = fma2(-e3.y, x3, d); da = fma2(e3.z, x3, da);
            }
            f2 o = tanh2(r) + tanh2(ra) + d + da + xw;
            *(f2*)(outb + (size_t)wa * LL) = o;
        }

        // ---- row b (headers already in flight) ----
        if (hb) {
            f2 xw = up2(xsw[wb * LC + l]);
            float cra = (b == 0) ? 0.0f : ccb.y;
            f2 r  = fma2(ccb.x, xw, (f2)bbb.x);
            f2 ra = fma2(cra,   xw, (f2)bbb.y);
            f2 d  = fma2(ccb.z, xw, (f2)bbb.z);
            f2 da = fma2(ccb.w, xw, (f2)bbb.w);
            for (int j = bf0; j < bf1; j += 4) {
                float4 e0 = eft[j], e1 = eft[j + 1], e2 = eft[j + 2], e3 = eft[j + 3];
                f2 x0 = up2(xsw[__float_as_int(e0.x) + l]);
                f2 x1 = up2(xsw[__float_as_int(e1.x) + l]);
                f2 x2 = up2(xsw[__float_as_int(e2.x) + l]);
                f2 x3 = up2(xsw[__float_as_int(e3.x) + l]);
                r = fma2(-e0.y, x0, r); ra = fma2(e0.z, x0, ra);
                r = fma2(-e1.y, x1, r); ra = fma2(e1.z, x1, ra);
                r = fma2(-e2.y, x2, r); ra = fma2(e2.z, x2, ra);
                r = fma2(-e3.y, x3, r); ra = fma2(e3.z, x3, ra);
            }
            for (int j = bt0; j < bt1; j += 4) {
                float4 e0 = ett[j], e1 = ett[j + 1], e2 = ett[j + 2], e3 = ett[j + 3];
                f2 x0 = up2(xsw[__float_as_int(e0.x) + l]);
                f2 x1 = up2(xsw[__float_as_int(e1.x) + l]);
                f2 x2 = up2(xsw[__float_as_int(e2.x) + l]);
                f2 x3 = up2(xsw[__float_as_int(e3.x) + l]);
                d = fma2(-e0.y, x0, d); da = fma2(e0.z, x0, da);
                d = fma2(-e1.y, x1, d); da = fma2(e1.z, x1, da);
                d = fma2(-e2.y, x2, d); da = fma2(e2.z, x2, da);
                d = fma2(-e3.y, x3, d); da = fma2(e3.z, x3, da);
            }
            f2 o = tanh2(r) + tanh2(ra) + d + da + xw;
            *(f2*)(outb + (size_t)wb * LL) = o;
        }
    }
}

extern "C" void kernel_launch(void* const* d_in, const int* in_sizes, int n_in,
                              void* d_out, int out_size, void* d_ws, size_t ws_size,
                              hipStream_t stream) {
    const float* inputs = (const float*)d_in[0];
    const int*   ind    = (const int*)d_in[1];
    const int*   efrom  = (const int*)d_in[2];
    const int*   eto    = (const int*)d_in[3];
    const float* wr     = (const float*)d_in[4];
    const float* wd     = (const float*)d_in[5];
    const float* wra    = (const float*)d_in[6];
    const float* wda    = (const float*)d_in[7];
    const float* br     = (const float*)d_in[8];
    const float* bd     = (const float*)d_in[9];
    const float* bra    = (const float*)d_in[10];
    const float* bda    = (const float*)d_in[11];
    float* out = (float*)d_out;

    char* ws = (char*)d_ws;
    int*    rp_f   = (int*)(ws + 0);
    int*    rp_t   = (int*)(ws + 1024);
    int*    perm_f = (int*)(ws + 2048);
    int*    nbr_f  = (int*)(ws + 12288);
    int*    perm_t = (int*)(ws + 22528);
    int*    nbr_t  = (int*)(ws + 32768);
    float4* ef     = (float4*)(ws + 43008);
    float4* et     = (float4*)(ws + 1026048);
    float4* ct4    = (float4*)(ws + 2009088);
    float4* bb4    = (float4*)(ws + 2088576);

    const int B = in_sizes[1];   // 64

    k_build_csr<<<dim3(1), dim3(256), 0, stream>>>(efrom, eto, rp_f, rp_t,
                                                   perm_f, nbr_f, perm_t, nbr_t);
    k_build_records<<<dim3(NT * EPMAX / 256), dim3(256), 0, stream>>>(
        rp_f, rp_t, perm_f, nbr_f, perm_t, nbr_t, wr, wra, wd, wda, ef, et);
    k_build_tables<<<dim3((NT * NN + 255) / 256), dim3(256), 0, stream>>>(
        rp_f, rp_t, perm_f, perm_t, wr, wra, wd, wda, br, bd, bra, bda, ct4, bb4);
    k_main<<<dim3(LL / LCC, B), dim3(256), 0, stream>>>(
        inputs, ind, rp_f, rp_t, ef, et, ct4, bb4, out);
}

// Round 4
// 444.719 us; speedup vs baseline: 1.3587x; 1.2339x over previous
//
#include <hip/hip_runtime.h>
#include <cstdint>
#include <cstddef>

#define NN 207      // nodes
#define NE 1722     // edges
#define NT 24       // time buckets (288/12)
#define LL 2048     // L
#define LCC 256     // columns per block (lane owns 4 cols)
#define EPMAX 2560  // padded slot capacity per direction (E + 3N = 2343 <= 2560)

// ---------------- ws layout (bytes) ----------------
// rp_f    @ 0       : int[256]  (N+1 used) from-sorted row ptrs (groups padded to x4)
// rp_t    @ 1024    : int[256]
// perm_f  @ 2048    : int[EPMAX]  edge id per slot, -1 = pad
// perm_t  @ 12288   : int[EPMAX]
// nbr16_f @ 22528   : u16[EPMAX]  neighbor node index (to[e]) per from-slot
// nbr16_t @ 27648   : u16[EPMAX]  neighbor node index (from[e]) per to-slot
// wf_f    @ 32768   : f2[NT*EPMAX] {wr, wra} per (t, from-slot); 0 on pads
// wf_t    @ 524288  : f2[NT*EPMAX] {wd, wda} per (t, to-slot)
// ct4     @ 1015808 : float4[NT*NN] {c_r, c_ra, c_d, c_da}
// bb4     @ 1095296 : float4[NT*NN] {b_r, b_ra, b_d, b_da}
// total ~1.12 MB

typedef float f2 __attribute__((ext_vector_type(2)));

__device__ __forceinline__ f2 tanh2(f2 x) {
    f2 o;
    float ex = __expf(2.0f * x.x), ey = __expf(2.0f * x.y);
    o.x = 1.0f - __fdividef(2.0f, ex + 1.0f);
    o.y = 1.0f - __fdividef(2.0f, ey + 1.0f);
    return o;
}

__device__ __forceinline__ f2 up2(unsigned int u) {   // dword of 2 bf16 -> f2
    f2 v;
    v.x = __uint_as_float(u << 16);
    v.y = __uint_as_float(u & 0xffff0000u);
    return v;
}

__device__ __forceinline__ unsigned short bf16_rne(float f) {  // manual RNE f32->bf16
    unsigned int u = __float_as_uint(f);
    u += 0x7FFFu + ((u >> 16) & 1u);
    return (unsigned short)(u >> 16);
}

__device__ __forceinline__ f2 fma2(float s, f2 x, f2 a) {
    f2 sv = s;
    return __builtin_elementwise_fma(sv, x, a);
}

// K1: padded CSR in both directions. Single block of 256 threads.
__global__ void k_build_csr(const int* __restrict__ efrom, const int* __restrict__ eto,
                            int* __restrict__ rp_f, int* __restrict__ rp_t,
                            int* __restrict__ perm_f, unsigned short* __restrict__ nbr16_f,
                            int* __restrict__ perm_t, unsigned short* __restrict__ nbr16_t) {
    __shared__ int cf[NN], ctn[NN], curf[NN], curt[NN];
    const int tid = threadIdx.x;
    for (int w = tid; w < NN; w += 256) { cf[w] = 0; ctn[w] = 0; }
    __syncthreads();
    for (int e = tid; e < NE; e += 256) {
        atomicAdd(&cf[efrom[e]], 1);
        atomicAdd(&ctn[eto[e]], 1);
    }
    __syncthreads();
    if (tid == 0) {      // exclusive scan, each row's slot count padded to multiple of 4
        int p = 0;
        for (int w = 0; w < NN; w++) { rp_f[w] = p; curf[w] = p; p += (cf[w] + 3) & ~3; }
        rp_f[NN] = p;
    }
    if (tid == 64) {
        int p = 0;
        for (int w = 0; w < NN; w++) { rp_t[w] = p; curt[w] = p; p += (ctn[w] + 3) & ~3; }
        rp_t[NN] = p;
    }
    __syncthreads();
    for (int j = tid; j < EPMAX; j += 256) {
        perm_f[j] = -1; perm_t[j] = -1; nbr16_f[j] = 0; nbr16_t[j] = 0;
    }
    __syncthreads();
    for (int e = tid; e < NE; e += 256) {
        int w  = efrom[e];
        int p  = atomicAdd(&curf[w], 1);
        perm_f[p] = e; nbr16_f[p] = (unsigned short)eto[e];
        int w2 = eto[e];
        int p2 = atomicAdd(&curt[w2], 1);
        perm_t[p2] = e; nbr16_t[p2] = (unsigned short)efrom[e];
    }
}

// K2: per-(t,slot) weight pairs; zeros on pad slots
__global__ void k_build_records(const int* __restrict__ perm_f, const int* __restrict__ perm_t,
                                const float* __restrict__ wr, const float* __restrict__ wra,
                                const float* __restrict__ wd, const float* __restrict__ wda,
                                f2* __restrict__ wf_f, f2* __restrict__ wf_t) {
    int gid = blockIdx.x * 256 + threadIdx.x;     // NT*EPMAX threads exactly
    int t = gid / EPMAX;
    int j = gid - t * EPMAX;
    if (t >= NT) return;
    int ef = perm_f[j];
    f2 a; a.x = 0.0f; a.y = 0.0f;
    if (ef >= 0) { a.x = wr[t * NE + ef]; a.y = wra[t * NE + ef]; }
    wf_f[gid] = a;
    int et = perm_t[j];
    f2 b; b.x = 0.0f; b.y = 0.0f;
    if (et >= 0) { b.x = wd[t * NE + et]; b.y = wda[t * NE + et]; }
    wf_t[gid] = b;
}

// K3: per-(t,w) diag coefficients (colsums) + packed biases
__global__ void k_build_tables(const int* __restrict__ rp_f, const int* __restrict__ rp_t,
                               const int* __restrict__ perm_f, const int* __restrict__ perm_t,
                               const float* __restrict__ wr, const float* __restrict__ wra,
                               const float* __restrict__ wd, const float* __restrict__ wda,
                               const float* __restrict__ br, const float* __restrict__ bd,
                               const float* __restrict__ bra, const float* __restrict__ bda,
                               float4* __restrict__ ct4, float4* __restrict__ bb4) {
    int gid = blockIdx.x * 256 + threadIdx.x;     // gid = t*NN + w
    if (gid >= NT * NN) return;
    int t = gid / NN;
    int w = gid - t * NN;
    float cr = 0.0f, cra = 0.0f, cd = 0.0f, cda = 0.0f;
    for (int j = rp_t[w]; j < rp_t[w + 1]; j++) {   // edges with to==w
        int eid = perm_t[j];
        if (eid >= 0) { cr += wr[t * NE + eid]; cra += wra[t * NE + eid]; }
    }
    for (int j = rp_f[w]; j < rp_f[w + 1]; j++) {   // edges with from==w
        int eid = perm_f[j];
        if (eid >= 0) { cd += wd[t * NE + eid]; cda += wda[t * NE + eid]; }
    }
    ct4[gid] = make_float4(cr, cra, cd, cda);
    bb4[gid] = make_float4(br[gid], bra[gid], bd[gid], bda[gid]);
}

// Main kernel: block = (256-col chunk, batch). 512 threads = 8 waves, 1 block/CU (LDS-bound).
// ALL inner-loop memory is LDS: records staged per block (~57 KB), x-tile bf16 (~106 KB).
// Lane l owns cols 4l..4l+3 (one ds_read_b64 gather per record = conflict-free: 128
// consecutive dwords over 32 banks = uniform 4 lanes/bank). Wave g handles rows w≡g (mod 8).
__global__ __launch_bounds__(512, 2) void k_main(
    const float* __restrict__ inputs, const int* __restrict__ ind,
    const int* __restrict__ rp_f, const int* __restrict__ rp_t,
    const unsigned short* __restrict__ nbr16_f, const unsigned short* __restrict__ nbr16_t,
    const f2* __restrict__ wf_f, const f2* __restrict__ wf_t,
    const float4* __restrict__ ct4, const float4* __restrict__ bb4,
    float* __restrict__ out) {
    __shared__ f2 lw_f[EPMAX];                 // 20480 B
    __shared__ f2 lw_t[EPMAX];                 // 20480 B
    __shared__ unsigned short xs[NN * LCC];    // 105984 B bf16 x-tile
    __shared__ unsigned short lnbr_f[EPMAX];   // 5120 B
    __shared__ unsigned short lnbr_t[EPMAX];   // 5120 B
    __shared__ int lrp_f[NN + 1];              // 832 B
    __shared__ int lrp_t[NN + 1];              // 832 B   -> total ~158.8 KB

    const int b     = blockIdx.y;
    const int chunk = blockIdx.x;
    const int tid   = threadIdx.x;
    const int t     = ind[b] / 12;

    // ---- stage records (straight copies, coalesced) ----
    {
        const f2* wff = wf_f + (size_t)t * EPMAX;
        const f2* wft = wf_t + (size_t)t * EPMAX;
        for (int i = tid; i < EPMAX; i += 512) {
            lw_f[i] = wff[i];
            lw_t[i] = wft[i];
            lnbr_f[i] = nbr16_f[i];
            lnbr_t[i] = nbr16_t[i];
        }
        for (int i = tid; i <= NN; i += 512) { lrp_f[i] = rp_f[i]; lrp_t[i] = rp_t[i]; }
    }
    // ---- stage x[b,0,:,chunk*256 .. +256) as bf16 ----
    const float* xbase = inputs + ((size_t)b * 2 * NN) * LL + (size_t)chunk * LCC;
    for (int i = tid; i < NN * 64; i += 512) {    // 207 rows x 64 float4
        int row = i >> 6;
        int c4  = (i & 63) << 2;
        float4 v = *(const float4*)(xbase + (size_t)row * LL + c4);
        ushort4 h;
        h.x = bf16_rne(v.x);
        h.y = bf16_rne(v.y);
        h.z = bf16_rne(v.z);
        h.w = bf16_rne(v.w);
        *(ushort4*)&xs[row * LCC + c4] = h;
    }
    __syncthreads();

    const int l  = tid & 63;
    const int w0 = tid >> 6;                      // 0..7
    const unsigned int lbase = (unsigned int)l * 8u;   // byte offset of this lane's 4 cols
    const char* xsb = (const char*)xs;
    const float4* ct4p = ct4 + (size_t)t * NN;
    const float4* bb4p = bb4 + (size_t)t * NN;
    float* outb = out + ((size_t)b * NN) * LL + (size_t)chunk * LCC + 4 * l;

    // prefetched headers for the first row
    int w = w0;
    int f0 = lrp_f[w], f1 = lrp_f[w + 1], g0 = lrp_t[w], g1 = lrp_t[w + 1];
    float4 cc = ct4p[w], bbv = bb4p[w];

    for (int k = 0; k < 26; k++, w += 8) {
        if (w >= NN) break;
        // prefetch next row's headers (hidden behind this row's record loops)
        int wn = w + 8;
        int nf0 = 0, nf1 = 0, ng0 = 0, ng1 = 0;
        float4 ncc = make_float4(0, 0, 0, 0), nbb = make_float4(0, 0, 0, 0);
        if (wn < NN) {
            nf0 = lrp_f[wn]; nf1 = lrp_f[wn + 1]; ng0 = lrp_t[wn]; ng1 = lrp_t[wn + 1];
            ncc = ct4p[wn]; nbb = bb4p[wn];
        }

        uint2 gxw = *(const uint2*)(xsb + (unsigned int)w * (LCC * 2) + lbase);
        f2 xlo = up2(gxw.x), xhi = up2(gxw.y);
        float cra = (b == 0) ? 0.0f : cc.y;   // colsum(RW[0]) == 0 analytically
        f2 r_lo  = fma2(cc.x, xlo, (f2)bbv.x), r_hi  = fma2(cc.x, xhi, (f2)bbv.x);
        f2 ra_lo = fma2(cra,  xlo, (f2)bbv.y), ra_hi = fma2(cra,  xhi, (f2)bbv.y);
        f2 d_lo  = fma2(cc.z, xlo, (f2)bbv.z), d_hi  = fma2(cc.z, xhi, (f2)bbv.z);
        f2 da_lo = fma2(cc.w, xlo, (f2)bbv.w), da_hi = fma2(cc.w, xhi, (f2)bbv.w);

        for (int j = f0; j < f1; j += 4) {          // groups padded to x4, zero-weight pads
            #pragma unroll
            for (int u = 0; u < 4; u++) {
                unsigned int n = lnbr_f[j + u];
                f2 wv = lw_f[j + u];
                uint2 g = *(const uint2*)(xsb + n * (LCC * 2) + lbase);
                f2 x_lo = up2(g.x), x_hi = up2(g.y);
                r_lo  = fma2(-wv.x, x_lo, r_lo);  r_hi  = fma2(-wv.x, x_hi, r_hi);
                ra_lo = fma2( wv.y, x_lo, ra_lo); ra_hi = fma2( wv.y, x_hi, ra_hi);
            }
        }
        for (int j = g0; j < g1; j += 4) {
            #pragma unroll
            for (int u = 0; u < 4; u++) {
                unsigned int n = lnbr_t[j + u];
                f2 wv = lw_t[j + u];
                uint2 g = *(const uint2*)(xsb + n * (LCC * 2) + lbase);
                f2 x_lo = up2(g.x), x_hi = up2(g.y);
                d_lo  = fma2(-wv.x, x_lo, d_lo);  d_hi  = fma2(-wv.x, x_hi, d_hi);
                da_lo = fma2( wv.y, x_lo, da_lo); da_hi = fma2( wv.y, x_hi, da_hi);
            }
        }

        f2 o_lo = tanh2(r_lo) + tanh2(ra_lo) + d_lo + da_lo + xlo;
        f2 o_hi = tanh2(r_hi) + tanh2(ra_hi) + d_hi + da_hi + xhi;
        float4 ov; ov.x = o_lo.x; ov.y = o_lo.y; ov.z = o_hi.x; ov.w = o_hi.y;
        *(float4*)(outb + (size_t)w * LL) = ov;

        f0 = nf0; f1 = nf1; g0 = ng0; g1 = ng1; cc = ncc; bbv = nbb;
    }
}

extern "C" void kernel_launch(void* const* d_in, const int* in_sizes, int n_in,
                              void* d_out, int out_size, void* d_ws, size_t ws_size,
                              hipStream_t stream) {
    const float* inputs = (const float*)d_in[0];
    const int*   ind    = (const int*)d_in[1];
    const int*   efrom  = (const int*)d_in[2];
    const int*   eto    = (const int*)d_in[3];
    const float* wr     = (const float*)d_in[4];
    const float* wd     = (const float*)d_in[5];
    const float* wra    = (const float*)d_in[6];
    const float* wda    = (const float*)d_in[7];
    const float* br     = (const float*)d_in[8];
    const float* bd     = (const float*)d_in[9];
    const float* bra    = (const float*)d_in[10];
    const float* bda    = (const float*)d_in[11];
    float* out = (float*)d_out;

    char* ws = (char*)d_ws;
    int*            rp_f    = (int*)(ws + 0);
    int*            rp_t    = (int*)(ws + 1024);
    int*            perm_f  = (int*)(ws + 2048);
    int*            perm_t  = (int*)(ws + 12288);
    unsigned short* nbr16_f = (unsigned short*)(ws + 22528);
    unsigned short* nbr16_t = (unsigned short*)(ws + 27648);
    f2*             wf_f    = (f2*)(ws + 32768);
    f2*             wf_t    = (f2*)(ws + 524288);
    float4*         ct4     = (float4*)(ws + 1015808);
    float4*         bb4     = (float4*)(ws + 1095296);

    const int B = in_sizes[1];   // 64

    k_build_csr<<<dim3(1), dim3(256), 0, stream>>>(efrom, eto, rp_f, rp_t,
                                                   perm_f, nbr16_f, perm_t, nbr16_t);
    k_build_records<<<dim3(NT * EPMAX / 256), dim3(256), 0, stream>>>(
        perm_f, perm_t, wr, wra, wd, wda, wf_f, wf_t);
    k_build_tables<<<dim3((NT * NN + 255) / 256), dim3(256), 0, stream>>>(
        rp_f, rp_t, perm_f, perm_t, wr, wra, wd, wda, br, bd, bra, bda, ct4, bb4);
    k_main<<<dim3(LL / LCC, B), dim3(512), 0, stream>>>(
        inputs, ind, rp_f, rp_t, nbr16_f, nbr16_t, wf_f, wf_t, ct4, bb4, out);
}